// Round 2
// baseline (3753.011 us; speedup 1.0000x reference)
//
#include <hip/hip_runtime.h>
#include <math.h>

#define TT 2048
#define UU 64
#define BB 256

// Fast activations on v_exp_f32 / v_rcp_f32 (~1e-7 abs err; threshold is 3.45e-6).
__device__ __forceinline__ float frcp(float x) { return __builtin_amdgcn_rcpf(x); }
__device__ __forceinline__ float fsigmoid(float x) { return frcp(1.0f + __expf(-x)); }
__device__ __forceinline__ float ftanh(float x) { return 1.0f - 2.0f * frcp(1.0f + __expf(2.0f * x)); }

// One wave (64 threads) per batch element, 256 blocks -> 1 per CU.
// Thread u owns unit u and ALL FOUR gate columns {u, 64+u, 128+u, 192+u} of W0
// in VGPRs (256 regs). Per step: 16 ds_read_b128 broadcasts of h, 256 FMAs,
// local activations -> h_u, one ds_write_b32. NO barriers anywhere in the loop
// (single-wave consistency). Layer 1 (1 unit) is lagged one step: butterfly-
// reduce hprev.W1 (24 ds_swizzle, overlaps matvec on the DS pipe), update
// (c1,h1) redundantly in all lanes, bank the dense output into a register and
// flush coalesced every 64 steps.
__global__ __launch_bounds__(64, 1) void lstm_ts_kernel(
    const float* __restrict__ x, const float* __restrict__ W0,
    const float* __restrict__ b0, const float* __restrict__ W1,
    const float* __restrict__ b1, const float* __restrict__ Wd,
    const float* __restrict__ bd, float* __restrict__ out)
{
    __shared__ float xbuf[TT];
    __shared__ __align__(16) float hbuf[UU];

    const int u = threadIdx.x;
    const int b = blockIdx.x;
    const float* xrow = x + b * TT;
    float* outrow = out + b * TT;

    // ---- prologue: stage x, sum of squares over T (in-wave) ----
    float ss = 0.f;
    #pragma unroll 4
    for (int i = 0; i < TT / 64; ++i) {
        float v = xrow[u + i * 64];
        xbuf[u + i * 64] = v;
        ss += v * v;
    }
    #pragma unroll
    for (int m = 1; m < 64; m <<= 1) ss += __shfl_xor(ss, m, 64);
    const float scale = 1.0f / sqrtf(fmaxf(ss, 1e-12f));  // precise, once

    // ---- per-thread weights: wcol[g][k] = W0 column (g*64+u), row (1+k) ----
    float wcol[4][UU];
    #pragma unroll
    for (int k = 0; k < UU; ++k) {
        #pragma unroll
        for (int g = 0; g < 4; ++g)
            wcol[g][k] = W0[(1 + k) * 256 + g * 64 + u];
    }
    float wxs[4], bc[4];
    #pragma unroll
    for (int g = 0; g < 4; ++g) {
        wxs[g] = W0[g * 64 + u] * scale;  // l2-norm scale folded into input weight
        bc[g]  = b0[g * 64 + u];
    }
    float w1v[4];
    #pragma unroll
    for (int g = 0; g < 4; ++g) w1v[g] = W1[u * 4 + g];
    const float w1h0 = W1[256], w1h1 = W1[257], w1h2 = W1[258], w1h3 = W1[259];
    const float b10 = b1[0], b11 = b1[1], b12 = b1[2], b13 = b1[3];
    const float wd = Wd[0], bdv = bd[0];

    hbuf[u] = 0.f;
    float c0 = 0.f, hprev = 0.f;
    float c1 = 0.f, h1 = 0.f;
    float oval = 0.f;
    __syncthreads();  // single wave; outside loop, harmless

    const float4* hv4 = reinterpret_cast<const float4*>(hbuf);

    for (int t = 0; t < TT; ++t) {
        // ---- layer-0 matvec: z[g] = b + xn*Wx + sum_k h[k]*W[k][g*64+u] ----
        float a[4][4];
        #pragma unroll
        for (int g = 0; g < 4; ++g) { a[g][0] = a[g][1] = a[g][2] = a[g][3] = 0.f; }
        #pragma unroll
        for (int i = 0; i < 16; ++i) {
            float4 h4 = hv4[i];
            #pragma unroll
            for (int g = 0; g < 4; ++g) {
                a[g][0] = fmaf(h4.x, wcol[g][4 * i + 0], a[g][0]);
                a[g][1] = fmaf(h4.y, wcol[g][4 * i + 1], a[g][1]);
                a[g][2] = fmaf(h4.z, wcol[g][4 * i + 2], a[g][2]);
                a[g][3] = fmaf(h4.w, wcol[g][4 * i + 3], a[g][3]);
            }
        }
        const float xr = xbuf[t];
        float z[4];
        #pragma unroll
        for (int g = 0; g < 4; ++g)
            z[g] = ((a[g][0] + a[g][1]) + (a[g][2] + a[g][3])) + fmaf(xr, wxs[g], bc[g]);

        // ---- layer-1 for step t-1 (lagged; shuffles overlap matvec DS/VALU) ----
        if (t > 0) {
            float p0 = hprev * w1v[0], p1 = hprev * w1v[1];
            float p2 = hprev * w1v[2], p3 = hprev * w1v[3];
            #pragma unroll
            for (int m = 1; m < 64; m <<= 1) {
                p0 += __shfl_xor(p0, m, 64);
                p1 += __shfl_xor(p1, m, 64);
                p2 += __shfl_xor(p2, m, 64);
                p3 += __shfl_xor(p3, m, 64);
            }
            const float z1i = p0 + fmaf(h1, w1h0, b10);
            const float z1j = p1 + fmaf(h1, w1h1, b11);
            const float z1f = p2 + fmaf(h1, w1h2, b12);
            const float z1o = p3 + fmaf(h1, w1h3, b13);
            c1 = fsigmoid(z1f + 1.0f) * c1 + fsigmoid(z1i) * ftanh(z1j);
            h1 = fsigmoid(z1o) * ftanh(c1);
            const int s = t - 1;
            const float ov = fmaf(h1, wd, bdv);
            if ((s & 63) == u) oval = ov;            // bank output in lane s&63
            if ((s & 63) == 63) outrow[(s & ~63) + u] = oval;  // coalesced flush
        }

        // ---- layer-0 cell update for unit u ----
        c0 = fsigmoid(z[2] + 1.0f) * c0 + fsigmoid(z[0]) * ftanh(z[1]);
        const float h = fsigmoid(z[3]) * ftanh(c0);
        hprev = h;
        hbuf[u] = h;  // in-wave RAW handled by lgkmcnt; no barrier
    }

    // ---- epilogue: layer-1 for s = TT-1, flush last 64 outputs ----
    {
        float p0 = hprev * w1v[0], p1 = hprev * w1v[1];
        float p2 = hprev * w1v[2], p3 = hprev * w1v[3];
        #pragma unroll
        for (int m = 1; m < 64; m <<= 1) {
            p0 += __shfl_xor(p0, m, 64);
            p1 += __shfl_xor(p1, m, 64);
            p2 += __shfl_xor(p2, m, 64);
            p3 += __shfl_xor(p3, m, 64);
        }
        const float z1i = p0 + fmaf(h1, w1h0, b10);
        const float z1j = p1 + fmaf(h1, w1h1, b11);
        const float z1f = p2 + fmaf(h1, w1h2, b12);
        const float z1o = p3 + fmaf(h1, w1h3, b13);
        c1 = fsigmoid(z1f + 1.0f) * c1 + fsigmoid(z1i) * ftanh(z1j);
        h1 = fsigmoid(z1o) * ftanh(c1);
        if (u == 63) oval = fmaf(h1, wd, bdv);
        outrow[TT - 64 + u] = oval;
    }
}

extern "C" void kernel_launch(void* const* d_in, const int* in_sizes, int n_in,
                              void* d_out, int out_size, void* d_ws, size_t ws_size,
                              hipStream_t stream) {
    const float* x  = (const float*)d_in[0];
    const float* W0 = (const float*)d_in[1];
    const float* b0 = (const float*)d_in[2];
    const float* W1 = (const float*)d_in[3];
    const float* b1 = (const float*)d_in[4];
    const float* Wd = (const float*)d_in[5];
    const float* bd = (const float*)d_in[6];
    float* out = (float*)d_out;
    lstm_ts_kernel<<<BB, 64, 0, stream>>>(x, W0, b0, W1, b1, Wd, bd, out);
}

// Round 3
// 1793.769 us; speedup vs baseline: 2.0922x; 2.0922x over previous
//
#include <hip/hip_runtime.h>
#include <math.h>

#define TT 2048
#define UU 64
#define BB 256

// Fast activations on v_exp_f32 / v_rcp_f32 (~1e-7 abs err; threshold 3.45e-6,
// validated absmax 9.5e-7 in round 2).
__device__ __forceinline__ float frcp(float x) { return __builtin_amdgcn_rcpf(x); }
__device__ __forceinline__ float fsigmoid(float x) { return frcp(1.0f + __expf(-x)); }
__device__ __forceinline__ float ftanh(float x) { return 1.0f - 2.0f * frcp(1.0f + __expf(2.0f * x)); }

// One block (256 thr = 4 waves) per batch element, 256 blocks = 1/CU.
// Thread t: gate g=t>>6, unit u=t&63, owns W0 column c=g*64+u in 16 NAMED
// float4 registers (named scalars are guaranteed SROA-promoted — rounds 1/2
// proved 64/256-element ARRAYS get left in scratch: VGPR_Count 60/152).
// Per step: 16 ds_read_b128 broadcasts of this wave's h replica, 64 FMAs -> z,
// z to double-buffered LDS, ONE barrier, then every wave redundantly updates
// (c0,h) for its lane's unit and rewrites its own h replica (no 2nd barrier).
// Layer 1 (1 unit): wave g butterfly-reduces column g of h.W1 into s1buf;
// wave 0 consumes it one step later (lagged) and stores the dense output.
__global__ __launch_bounds__(256, 1) void lstm_ts_kernel(
    const float* __restrict__ x, const float* __restrict__ W0,
    const float* __restrict__ b0, const float* __restrict__ W1,
    const float* __restrict__ b1, const float* __restrict__ Wd,
    const float* __restrict__ bd, float* __restrict__ out)
{
    __shared__ float xbuf[TT];
    __shared__ float zbuf[2][256];
    __shared__ __align__(16) float hbuf[4][UU];
    __shared__ float s1buf[2][4];
    __shared__ float red[4];

    const int tid = threadIdx.x;
    const int g = tid >> 6;
    const int u = tid & 63;
    const int b = blockIdx.x;
    const float* xrow = x + b * TT;

    // ---- prologue: stage x, sum of squares over T ----
    float ss = 0.f;
    for (int t = tid; t < TT; t += 256) {
        float v = xrow[t];
        xbuf[t] = v;
        ss += v * v;
    }
    #pragma unroll
    for (int m = 1; m < 64; m <<= 1) ss += __shfl_xor(ss, m, 64);
    if (u == 0) red[g] = ss;
    __syncthreads();
    const float sq = red[0] + red[1] + red[2] + red[3];
    const float scale = 1.0f / sqrtf(fmaxf(sq, 1e-12f));  // precise, once

    // ---- weights: 16 named float4 = 64 VGPRs, guaranteed promotion ----
    float4 W00, W01, W02, W03, W04, W05, W06, W07,
           W08, W09, W10, W11, W12, W13, W14, W15;
    #define LOADW(R, i)                                   \
        R.x = W0[(1 + 4 * i + 0) * 256 + tid];            \
        R.y = W0[(1 + 4 * i + 1) * 256 + tid];            \
        R.z = W0[(1 + 4 * i + 2) * 256 + tid];            \
        R.w = W0[(1 + 4 * i + 3) * 256 + tid];
    LOADW(W00, 0)  LOADW(W01, 1)  LOADW(W02, 2)  LOADW(W03, 3)
    LOADW(W04, 4)  LOADW(W05, 5)  LOADW(W06, 6)  LOADW(W07, 7)
    LOADW(W08, 8)  LOADW(W09, 9)  LOADW(W10, 10) LOADW(W11, 11)
    LOADW(W12, 12) LOADW(W13, 13) LOADW(W14, 14) LOADW(W15, 15)
    #undef LOADW

    const float wxs = W0[tid] * scale;   // l2-norm scale folded into input weight
    const float bc  = b0[tid];
    const float w1v = W1[u * 4 + g];
    const float w1h0 = W1[256], w1h1 = W1[257], w1h2 = W1[258], w1h3 = W1[259];
    const float b10 = b1[0], b11 = b1[1], b12 = b1[2], b13 = b1[3];
    const float wd = Wd[0], bdv = bd[0];

    hbuf[g][u] = 0.f;
    const float4* hv4 = reinterpret_cast<const float4*>(&hbuf[g][0]);

    float c0 = 0.f;
    float h1 = 0.f, c1 = 0.f;
    __syncthreads();

    for (int t = 0; t < TT; ++t) {
        const int p = t & 1;
        const float xr = xbuf[t];

        float a0 = 0.f, a1 = 0.f, a2 = 0.f, a3 = 0.f;
        #define STEPW(R, i) {                              \
            float4 h4 = hv4[i];                            \
            a0 = fmaf(h4.x, R.x, a0);                      \
            a1 = fmaf(h4.y, R.y, a1);                      \
            a2 = fmaf(h4.z, R.z, a2);                      \
            a3 = fmaf(h4.w, R.w, a3); }
        STEPW(W00, 0)  STEPW(W01, 1)  STEPW(W02, 2)  STEPW(W03, 3)
        STEPW(W04, 4)  STEPW(W05, 5)  STEPW(W06, 6)  STEPW(W07, 7)
        STEPW(W08, 8)  STEPW(W09, 9)  STEPW(W10, 10) STEPW(W11, 11)
        STEPW(W12, 12) STEPW(W13, 13) STEPW(W14, 14) STEPW(W15, 15)
        #undef STEPW
        const float z = ((a0 + a1) + (a2 + a3)) + fmaf(xr, wxs, bc);
        zbuf[p][tid] = z;
        __syncthreads();

        // every wave redundantly updates unit u (keeps h replicated, no 2nd barrier)
        const float zi = zbuf[p][u];
        const float zj = zbuf[p][64 + u];
        const float zf = zbuf[p][128 + u];
        const float zo = zbuf[p][192 + u];
        c0 = fsigmoid(zf + 1.0f) * c0 + fsigmoid(zi) * ftanh(zj);
        const float h = fsigmoid(zo) * ftanh(c0);
        hbuf[g][u] = h;

        // layer-1 partial: wave g reduces column g of h.W1
        float pc = h * w1v;
        #pragma unroll
        for (int m = 1; m < 64; m <<= 1) pc += __shfl_xor(pc, m, 64);
        if (u == 0) s1buf[p][g] = pc;

        // wave 0: consume step t-1's layer-1 sums (visible since barrier above)
        if (g == 0 && t > 0) {
            const int q = p ^ 1;
            const float z1i = s1buf[q][0] + fmaf(h1, w1h0, b10);
            const float z1j = s1buf[q][1] + fmaf(h1, w1h1, b11);
            const float z1f = s1buf[q][2] + fmaf(h1, w1h2, b12);
            const float z1o = s1buf[q][3] + fmaf(h1, w1h3, b13);
            c1 = fsigmoid(z1f + 1.0f) * c1 + fsigmoid(z1i) * ftanh(z1j);
            h1 = fsigmoid(z1o) * ftanh(c1);
            if (u == 0) out[b * TT + (t - 1)] = fmaf(h1, wd, bdv);
        }
    }

    // flush the last timestep's layer-1 update
    __syncthreads();
    if (g == 0) {
        const int q = (TT - 1) & 1;
        const float z1i = s1buf[q][0] + fmaf(h1, w1h0, b10);
        const float z1j = s1buf[q][1] + fmaf(h1, w1h1, b11);
        const float z1f = s1buf[q][2] + fmaf(h1, w1h2, b12);
        const float z1o = s1buf[q][3] + fmaf(h1, w1h3, b13);
        c1 = fsigmoid(z1f + 1.0f) * c1 + fsigmoid(z1i) * ftanh(z1j);
        h1 = fsigmoid(z1o) * ftanh(c1);
        if (u == 0) out[b * TT + (TT - 1)] = fmaf(h1, wd, bdv);
    }
}

extern "C" void kernel_launch(void* const* d_in, const int* in_sizes, int n_in,
                              void* d_out, int out_size, void* d_ws, size_t ws_size,
                              hipStream_t stream) {
    const float* x  = (const float*)d_in[0];
    const float* W0 = (const float*)d_in[1];
    const float* b0 = (const float*)d_in[2];
    const float* W1 = (const float*)d_in[3];
    const float* b1 = (const float*)d_in[4];
    const float* Wd = (const float*)d_in[5];
    const float* bd = (const float*)d_in[6];
    float* out = (float*)d_out;
    lstm_ts_kernel<<<BB, 256, 0, stream>>>(x, W0, b0, W1, b1, Wd, bd, out);
}